// Round 1
// baseline (326.959 us; speedup 1.0000x reference)
//
#include <hip/hip_runtime.h>
#include <stdint.h>

typedef unsigned short u16;
typedef short bf8_t __attribute__((ext_vector_type(8)));   // 8 bf16 = 4 VGPR
typedef float f4_t  __attribute__((ext_vector_type(4)));

#define LOG2E 1.44269504088896340736f

static __device__ __forceinline__ u16 f2bf(float f){
  union { float f; uint32_t u; } v; v.f = f;
  uint32_t r = v.u + 0x7FFFu + ((v.u >> 16) & 1u);   // RNE
  return (u16)(r >> 16);
}

// ---------------- pre-kernels ----------------

// convert qkv_w [768*256] and proj_w [256*256] fp32 -> bf16
__global__ void wconv_kernel(const float* __restrict__ qkvw, const float* __restrict__ projw,
                             u16* __restrict__ wq, u16* __restrict__ wp){
  int i4 = blockIdx.x * blockDim.x + threadIdx.x;   // 0..65535, 4 floats each
  const float* src; u16* dst; int off;
  if (i4 < 49152){ src = qkvw; dst = wq; off = i4 * 4; }
  else           { src = projw; dst = wp; off = (i4 - 49152) * 4; }
  float4 v = *reinterpret_cast<const float4*>(src + off);
  uint2 p;
  p.x = (uint32_t)f2bf(v.x) | ((uint32_t)f2bf(v.y) << 16);
  p.y = (uint32_t)f2bf(v.z) | ((uint32_t)f2bf(v.w) << 16);
  *reinterpret_cast<uint2*>(dst + off) = p;
}

// CPB MLP: tbl[i][h] = relu(coords[i]@w1^T + b1) @ w2[h]^T   (225 rows, 8 heads)
__global__ void cpbmlp_kernel(const float* __restrict__ tab, const float* __restrict__ w1,
                              const float* __restrict__ b1, const float* __restrict__ w2,
                              float* __restrict__ tbl){
  int u = blockIdx.x * blockDim.x + threadIdx.x;
  if (u >= 225 * 8) return;
  int i = u >> 3, h = u & 7;
  float c0 = tab[2*i], c1 = tab[2*i+1];
  const float* w2h = w2 + h * 512;
  float acc = 0.f;
  for (int j = 0; j < 512; j++){
    float hv = fmaf(c1, w1[2*j+1], fmaf(c0, w1[2*j], b1[j]));
    hv = fmaxf(hv, 0.f);
    acc = fmaf(hv, w2h[j], acc);
  }
  tbl[i*8 + h] = acc;
}

// gather: bias[h*4096 + n*64 + m] = 16*sigmoid(tbl[idx[n,m]][h]) * log2(e)
// plus folded per-head scale: scf[h] = exp(min(scale[h], log(100))) * log2(e)
__global__ void cpbgather_kernel(const float* __restrict__ tbl, const int* __restrict__ idx,
                                 const float* __restrict__ scale, float* __restrict__ bias,
                                 float* __restrict__ scf){
  int u = blockIdx.x * blockDim.x + threadIdx.x;   // 0..32767
  int h = u >> 12, nm = u & 4095;
  int id = idx[nm];
  float xv = tbl[id*8 + h];
  float s = 1.f / (1.f + expf(-xv));
  bias[u] = 16.f * s * LOG2E;
  if (u < 8){
    float sc = fminf(scale[u], 4.6051701859880913680f);  // log(100)
    scf[u] = expf(sc) * LOG2E;
  }
}

// ---------------- main fused kernel ----------------
// One block per window. 512 threads = 8 waves.
// LDS strides chosen so row-stride (in dwords) == 4 mod 32 -> conflict-free b128 reads.
#define XS  264   // x / O tile stride (256+8) bf16; 528 B = 132 dw == 4 mod 32
#define QKS 520   // q,k tile stride (512+8) bf16; 1040 B = 260 dw == 4 mod 32
#define VTS 72    // v^T tile stride (64+8) bf16;  144 B = 36 dw  == 4 mod 32

__global__ __launch_bounds__(512, 2)
void winattn_kernel(const float* __restrict__ x, const u16* __restrict__ wq,
                    const u16* __restrict__ wp, const float* __restrict__ qb,
                    const float* __restrict__ vbias, const float* __restrict__ biasTbl,
                    const float* __restrict__ scf, const float* __restrict__ projb,
                    float* __restrict__ out){
  __shared__ u16 xlds[64 * XS];     // x bf16 in phase1; O bf16 in phase2/3
  __shared__ u16 qklds[64 * QKS];   // q|k bf16 (cols 0..255 q, 256..511 k); P scratch in ph2
  __shared__ u16 vtlds[256 * VTS];  // v transposed: [d_global 0..255][key 0..63]

  const int b = blockIdx.x;
  const int t = threadIdx.x;
  const int w = t >> 6, lane = t & 63;
  const int l15 = lane & 15, l4 = lane >> 4;

  // ---- phase 0: stage x[b] -> LDS bf16 ----
  {
    const float* xg = x + (size_t)b * 16384;
    #pragma unroll
    for (int i = 0; i < 8; i++){
      int fi = t + 512 * i;                       // float4 index 0..4095
      float4 v = *reinterpret_cast<const float4*>(xg + fi * 4);
      uint2 p;
      p.x = (uint32_t)f2bf(v.x) | ((uint32_t)f2bf(v.y) << 16);
      p.y = (uint32_t)f2bf(v.z) | ((uint32_t)f2bf(v.w) << 16);
      int row = fi >> 6, c = (fi & 63) * 4;
      *reinterpret_cast<uint2*>(&xlds[row * XS + c]) = p;
    }
  }
  __syncthreads();

  // ---- phase 1: QKV GEMM (wave w owns cols [96w, 96w+96)) + bias + q/k norm ----
  {
    const int jb = w * 96;
    f4_t acc[4][6];
    #pragma unroll
    for (int g = 0; g < 3; g++){
      int gcol = jb + 32 * g;                      // head-aligned 32-col group
      float b0 = 0.f, b1v = 0.f;
      if (gcol < 256){ b0 = qb[gcol + l15]; b1v = qb[gcol + 16 + l15]; }
      else if (gcol >= 512){ b0 = vbias[gcol - 512 + l15]; b1v = vbias[gcol - 496 + l15]; }
      #pragma unroll
      for (int mt = 0; mt < 4; mt++){
        acc[mt][2*g]   = f4_t{b0, b0, b0, b0};     // bias as MFMA C-init
        acc[mt][2*g+1] = f4_t{b1v, b1v, b1v, b1v};
      }
    }
    #pragma unroll 2
    for (int ks = 0; ks < 8; ks++){
      int k0 = ks * 32 + l4 * 8;
      bf8_t a[4];
      #pragma unroll
      for (int mt = 0; mt < 4; mt++)
        a[mt] = *reinterpret_cast<const bf8_t*>(&xlds[(l15 + 16*mt) * XS + k0]);
      #pragma unroll
      for (int nt = 0; nt < 6; nt++){
        bf8_t bw = *reinterpret_cast<const bf8_t*>(&wq[(size_t)(jb + nt*16 + l15) * 256 + k0]);
        #pragma unroll
        for (int mt = 0; mt < 4; mt++)
          acc[mt][nt] = __builtin_amdgcn_mfma_f32_16x16x32_bf16(a[mt], bw, acc[mt][nt], 0, 0, 0);
      }
    }
    #pragma unroll
    for (int g = 0; g < 3; g++){
      int gcol = jb + 32 * g;
      if (gcol < 512){
        // q or k: L2-normalize each row over this head's 32 cols; fold scale into q
        float scf_ = 1.0f;
        if (gcol < 256) scf_ = scf[gcol >> 5];
        #pragma unroll
        for (int mt = 0; mt < 4; mt++){
          #pragma unroll
          for (int r = 0; r < 4; r++){
            float v0 = acc[mt][2*g][r], v1 = acc[mt][2*g+1][r];
            float sq = v0*v0 + v1*v1;
            sq += __shfl_xor(sq, 1); sq += __shfl_xor(sq, 2);
            sq += __shfl_xor(sq, 4); sq += __shfl_xor(sq, 8);
            float iv = scf_ / fmaxf(sqrtf(sq), 1e-12f);
            acc[mt][2*g][r]   = v0 * iv;
            acc[mt][2*g+1][r] = v1 * iv;
          }
        }
        #pragma unroll
        for (int mt = 0; mt < 4; mt++)
          #pragma unroll
          for (int dn = 0; dn < 2; dn++)
            #pragma unroll
            for (int r = 0; r < 4; r++)
              qklds[(16*mt + l4*4 + r) * QKS + gcol + dn*16 + l15] = f2bf(acc[mt][2*g+dn][r]);
      } else {
        // v: store transposed (C-layout lane already holds one column)
        #pragma unroll
        for (int mt = 0; mt < 4; mt++)
          #pragma unroll
          for (int dn = 0; dn < 2; dn++)
            #pragma unroll
            for (int r = 0; r < 4; r++)
              vtlds[(gcol - 512 + dn*16 + l15) * VTS + 16*mt + l4*4 + r] = f2bf(acc[mt][2*g+dn][r]);
      }
    }
  }
  __syncthreads();

  // ---- phase 2: attention, head h = w (wave-private) ----
  float inv_r[4][4];
  {
    const int h = w;
    const int qc = 32 * h, kc = 256 + 32 * h;
    // CPB bias (already *log2e) preloaded straight into MFMA C operand
    f4_t accS[4][4];
    const float* bh = biasTbl + h * 4096;
    #pragma unroll
    for (int mt = 0; mt < 4; mt++)
      #pragma unroll
      for (int nt = 0; nt < 4; nt++)
        #pragma unroll
        for (int r = 0; r < 4; r++)
          accS[mt][nt][r] = bh[(16*mt + l4*4 + r) * 64 + nt*16 + l15];
    bf8_t qa[4], kb[4];
    #pragma unroll
    for (int mt = 0; mt < 4; mt++)
      qa[mt] = *reinterpret_cast<const bf8_t*>(&qklds[(l15 + 16*mt) * QKS + qc + l4*8]);
    #pragma unroll
    for (int nt = 0; nt < 4; nt++)
      kb[nt] = *reinterpret_cast<const bf8_t*>(&qklds[(l15 + 16*nt) * QKS + kc + l4*8]);
    #pragma unroll
    for (int mt = 0; mt < 4; mt++)
      #pragma unroll
      for (int nt = 0; nt < 4; nt++)
        accS[mt][nt] = __builtin_amdgcn_mfma_f32_16x16x32_bf16(qa[mt], kb[nt], accS[mt][nt], 0, 0, 0);
    // softmax (logits already in log2 domain)
    #pragma unroll
    for (int mt = 0; mt < 4; mt++){
      #pragma unroll
      for (int r = 0; r < 4; r++){
        float mx = fmaxf(fmaxf(accS[mt][0][r], accS[mt][1][r]),
                         fmaxf(accS[mt][2][r], accS[mt][3][r]));
        mx = fmaxf(mx, __shfl_xor(mx, 1)); mx = fmaxf(mx, __shfl_xor(mx, 2));
        mx = fmaxf(mx, __shfl_xor(mx, 4)); mx = fmaxf(mx, __shfl_xor(mx, 8));
        float s = 0.f;
        #pragma unroll
        for (int nt = 0; nt < 4; nt++){
          float p = exp2f(accS[mt][nt][r] - mx);
          accS[mt][nt][r] = p; s += p;
        }
        s += __shfl_xor(s, 1); s += __shfl_xor(s, 2);
        s += __shfl_xor(s, 4); s += __shfl_xor(s, 8);
        inv_r[mt][r] = 1.0f / s;                   // defer division to O epilogue
      }
    }
    // PV in two key-halves; P staged bf16 into this wave's dead q/k regions
    f4_t accO[4][2];
    #pragma unroll
    for (int mt = 0; mt < 4; mt++){ accO[mt][0] = f4_t{0,0,0,0}; accO[mt][1] = f4_t{0,0,0,0}; }
    #pragma unroll
    for (int kh = 0; kh < 2; kh++){
      int sb = kh ? kc : qc;
      #pragma unroll
      for (int mt = 0; mt < 4; mt++)
        #pragma unroll
        for (int dn = 0; dn < 2; dn++)
          #pragma unroll
          for (int r = 0; r < 4; r++)
            qklds[(16*mt + l4*4 + r) * QKS + sb + dn*16 + l15] = f2bf(accS[mt][2*kh+dn][r]);
      asm volatile("s_waitcnt lgkmcnt(0)" ::: "memory");
      __builtin_amdgcn_sched_barrier(0);
      bf8_t pa[4], vv[2];
      #pragma unroll
      for (int mt = 0; mt < 4; mt++)
        pa[mt] = *reinterpret_cast<const bf8_t*>(&qklds[(l15 + 16*mt) * QKS + sb + l4*8]);
      #pragma unroll
      for (int nt = 0; nt < 2; nt++)
        vv[nt] = *reinterpret_cast<const bf8_t*>(&vtlds[(32*h + nt*16 + l15) * VTS + 32*kh + l4*8]);
      #pragma unroll
      for (int mt = 0; mt < 4; mt++)
        #pragma unroll
        for (int nt = 0; nt < 2; nt++)
          accO[mt][nt] = __builtin_amdgcn_mfma_f32_16x16x32_bf16(pa[mt], vv[nt], accO[mt][nt], 0, 0, 0);
    }
    // O (scaled by 1/rowsum) -> bf16 into xlds-aliased O buffer
    #pragma unroll
    for (int mt = 0; mt < 4; mt++)
      #pragma unroll
      for (int nt = 0; nt < 2; nt++)
        #pragma unroll
        for (int r = 0; r < 4; r++)
          xlds[(16*mt + l4*4 + r) * XS + 32*h + nt*16 + l15] = f2bf(accO[mt][nt][r] * inv_r[mt][r]);
  }
  __syncthreads();

  // ---- phase 3: output projection (wave w owns cols [32w, 32w+32)) ----
  {
    const int jb3 = 32 * w;
    f4_t accP[4][2];
    #pragma unroll
    for (int mt = 0; mt < 4; mt++){ accP[mt][0] = f4_t{0,0,0,0}; accP[mt][1] = f4_t{0,0,0,0}; }
    #pragma unroll 2
    for (int ks = 0; ks < 8; ks++){
      int k0 = ks * 32 + l4 * 8;
      bf8_t a[4];
      #pragma unroll
      for (int mt = 0; mt < 4; mt++)
        a[mt] = *reinterpret_cast<const bf8_t*>(&xlds[(l15 + 16*mt) * XS + k0]);
      bf8_t bw[2];
      #pragma unroll
      for (int nt = 0; nt < 2; nt++)
        bw[nt] = *reinterpret_cast<const bf8_t*>(&wp[(size_t)(jb3 + nt*16 + l15) * 256 + k0]);
      #pragma unroll
      for (int mt = 0; mt < 4; mt++)
        #pragma unroll
        for (int nt = 0; nt < 2; nt++)
          accP[mt][nt] = __builtin_amdgcn_mfma_f32_16x16x32_bf16(a[mt], bw[nt], accP[mt][nt], 0, 0, 0);
    }
    float pb0 = projb[jb3 + l15], pb1 = projb[jb3 + 16 + l15];
    float* og = out + (size_t)b * 16384;
    #pragma unroll
    for (int mt = 0; mt < 4; mt++)
      #pragma unroll
      for (int nt = 0; nt < 2; nt++)
        #pragma unroll
        for (int r = 0; r < 4; r++)
          og[(16*mt + l4*4 + r) * 256 + jb3 + nt*16 + l15] = accP[mt][nt][r] + (nt ? pb1 : pb0);
  }
}

// ---------------- launch ----------------
extern "C" void kernel_launch(void* const* d_in, const int* in_sizes, int n_in,
                              void* d_out, int out_size, void* d_ws, size_t ws_size,
                              hipStream_t stream){
  const float* x     = (const float*)d_in[0];
  const float* qkvw  = (const float*)d_in[1];
  const float* qb    = (const float*)d_in[2];
  const float* vb    = (const float*)d_in[3];
  const float* scale = (const float*)d_in[4];
  const float* w1    = (const float*)d_in[5];
  const float* b1    = (const float*)d_in[6];
  const float* w2    = (const float*)d_in[7];
  const float* pw    = (const float*)d_in[8];
  const float* pb    = (const float*)d_in[9];
  const float* tab   = (const float*)d_in[10];
  const int*   idx   = (const int*)d_in[11];
  float* out = (float*)d_out;

  char* ws = (char*)d_ws;
  u16*   wqb  = (u16*)ws;                    // 393216 B : qkv_w bf16
  u16*   wpb  = (u16*)(ws + 393216);         // 131072 B : proj_w bf16
  float* bias = (float*)(ws + 524288);       // 131072 B : 16*sigmoid(cpb)*log2e, [h][n][m]
  float* tbl  = (float*)(ws + 655360);       //   7200 B : cpb MLP out [225][8]
  float* scfp = (float*)(ws + 662560);       //     32 B : folded per-head scale

  hipLaunchKernelGGL(wconv_kernel,    dim3(256), dim3(256), 0, stream, qkvw, pw, wqb, wpb);
  hipLaunchKernelGGL(cpbmlp_kernel,   dim3(8),   dim3(256), 0, stream, tab, w1, b1, w2, tbl);
  hipLaunchKernelGGL(cpbgather_kernel,dim3(128), dim3(256), 0, stream, tbl, idx, scale, bias, scfp);
  hipLaunchKernelGGL(winattn_kernel,  dim3(2048), dim3(512), 0, stream,
                     x, wqb, wpb, qb, vb, bias, scfp, pb, out);
}

// Round 2
// 230.250 us; speedup vs baseline: 1.4200x; 1.4200x over previous
//
#include <hip/hip_runtime.h>
#include <stdint.h>

typedef unsigned short u16;
typedef short bf8_t __attribute__((ext_vector_type(8)));   // 8 bf16 = 4 VGPR
typedef float f4_t  __attribute__((ext_vector_type(4)));

#define LOG2E 1.44269504088896340736f

static __device__ __forceinline__ u16 f2bf(float f){
  union { float f; uint32_t u; } v; v.f = f;
  uint32_t r = v.u + 0x7FFFu + ((v.u >> 16) & 1u);   // RNE
  return (u16)(r >> 16);
}

// ---------------- pre-kernels ----------------

// convert qkv_w [768*256] and proj_w [256*256] fp32 -> bf16
__global__ void wconv_kernel(const float* __restrict__ qkvw, const float* __restrict__ projw,
                             u16* __restrict__ wq, u16* __restrict__ wp){
  int i4 = blockIdx.x * blockDim.x + threadIdx.x;   // 0..65535, 4 floats each
  const float* src; u16* dst; int off;
  if (i4 < 49152){ src = qkvw; dst = wq; off = i4 * 4; }
  else           { src = projw; dst = wp; off = (i4 - 49152) * 4; }
  float4 v = *reinterpret_cast<const float4*>(src + off);
  uint2 p;
  p.x = (uint32_t)f2bf(v.x) | ((uint32_t)f2bf(v.y) << 16);
  p.y = (uint32_t)f2bf(v.z) | ((uint32_t)f2bf(v.w) << 16);
  *reinterpret_cast<uint2*>(dst + off) = p;
}

// CPB MLP: tbl[i][h] = relu(coords[i]@w1^T + b1) @ w2[h]^T   (225 rows, 8 heads)
__global__ void cpbmlp_kernel(const float* __restrict__ tab, const float* __restrict__ w1,
                              const float* __restrict__ b1, const float* __restrict__ w2,
                              float* __restrict__ tbl){
  int u = blockIdx.x * blockDim.x + threadIdx.x;
  if (u >= 225 * 8) return;
  int i = u >> 3, h = u & 7;
  float c0 = tab[2*i], c1 = tab[2*i+1];
  const float* w2h = w2 + h * 512;
  float acc = 0.f;
  for (int j = 0; j < 512; j++){
    float hv = fmaf(c1, w1[2*j+1], fmaf(c0, w1[2*j], b1[j]));
    hv = fmaxf(hv, 0.f);
    acc = fmaf(hv, w2h[j], acc);
  }
  tbl[i*8 + h] = acc;
}

// gather into MFMA C-fragment order:
// biasF[(((h*4+mt)*4+nt)*64 + lane)*4 + r] = 16*sigmoid(cpb[row,col,h]) * log2e
// with row = 16mt + 4*(lane>>4) + r, col = 16nt + (lane&15).
// Also folded per-head scale: scf[h] = exp(min(scale[h], log(100))) * log2(e)
__global__ void cpbgather_kernel(const float* __restrict__ tbl, const int* __restrict__ idx,
                                 const float* __restrict__ scale, float* __restrict__ biasF,
                                 float* __restrict__ scf){
  int u = blockIdx.x * blockDim.x + threadIdx.x;   // 0..32767
  int r  = u & 3;
  int lane = (u >> 2) & 63;
  int nt = (u >> 8) & 3;
  int mt = (u >> 10) & 3;
  int hh = (u >> 12) & 7;
  int row = 16*mt + 4*(lane >> 4) + r;
  int col = 16*nt + (lane & 15);
  int id = idx[row*64 + col];
  float xv = tbl[id*8 + hh];
  float s = 1.f / (1.f + expf(-xv));
  biasF[u] = 16.f * s * LOG2E;
  if (u < 8){
    float sc = fminf(scale[u], 4.6051701859880913680f);  // log(100)
    scf[u] = expf(sc) * LOG2E;
  }
}

// ---------------- main fused kernel ----------------
// One block per window, 512 threads = 8 waves, wave w owns head w end-to-end.
// LDS: x tile (33.8 KB) + 8 per-wave 5 KB transpose buffers = 74.75 KB
//   -> 2 blocks/CU (16 waves/CU). __launch_bounds__(512,4) caps regs at 128.
#define XS  264   // x / O tile stride (256+8) bf16; 528 B
#define WBS 2560  // per-wave scratch: 64 rows * 40 u16 (5120 B), reused q->k->vT->P

#define LDSFENCE() do { asm volatile("s_waitcnt lgkmcnt(0)" ::: "memory"); \
                        __builtin_amdgcn_sched_barrier(0); } while(0)

__global__ __launch_bounds__(512, 4)
void winattn_kernel(const float* __restrict__ x, const u16* __restrict__ wq,
                    const u16* __restrict__ wp, const float* __restrict__ qb,
                    const float* __restrict__ vbias, const float* __restrict__ biasF,
                    const float* __restrict__ scf, const float* __restrict__ projb,
                    float* __restrict__ out){
  __shared__ u16 xlds[64 * XS];     // x bf16 in phase1; O bf16 afterwards
  __shared__ u16 wbuf[8][WBS];      // per-wave transpose scratch

  const int b = blockIdx.x;
  const int t = threadIdx.x;
  const int w = t >> 6, lane = t & 63;
  const int l15 = lane & 15, l4 = lane >> 4;
  const int h = w;

  // ---- phase 0: stage x[b] -> LDS bf16 ----
  {
    const float* xg = x + (size_t)b * 16384;
    #pragma unroll
    for (int i = 0; i < 8; i++){
      int fi = t + 512 * i;                       // float4 index 0..4095
      float4 v = *reinterpret_cast<const float4*>(xg + fi * 4);
      uint2 p;
      p.x = (uint32_t)f2bf(v.x) | ((uint32_t)f2bf(v.y) << 16);
      p.y = (uint32_t)f2bf(v.z) | ((uint32_t)f2bf(v.w) << 16);
      int row = fi >> 6, c = (fi & 63) * 4;
      *reinterpret_cast<uint2*>(&xlds[row * XS + c]) = p;
    }
  }
  __syncthreads();

  u16* wb = wbuf[w];
  bf8_t qa[4], kb[4], vv[2][2];

  // ---- pass A: q,k for head h ----
  {
    f4_t accA[4][4];                               // [mt][{q0,q1,k0,k1}]
    float bq0 = qb[32*h + l15], bq1 = qb[32*h + 16 + l15];
    #pragma unroll
    for (int mt = 0; mt < 4; mt++){
      accA[mt][0] = f4_t{bq0, bq0, bq0, bq0};
      accA[mt][1] = f4_t{bq1, bq1, bq1, bq1};
      accA[mt][2] = f4_t{0, 0, 0, 0};
      accA[mt][3] = f4_t{0, 0, 0, 0};
    }
    const u16* wr0 = wq + (size_t)(       32*h      + l15) * 256;
    const u16* wr1 = wq + (size_t)(       32*h + 16 + l15) * 256;
    const u16* wr2 = wq + (size_t)(256 +  32*h      + l15) * 256;
    const u16* wr3 = wq + (size_t)(256 +  32*h + 16 + l15) * 256;
    #pragma unroll 2
    for (int ks = 0; ks < 8; ks++){
      int k0 = ks * 32 + l4 * 8;
      bf8_t a[4];
      #pragma unroll
      for (int mt = 0; mt < 4; mt++)
        a[mt] = *reinterpret_cast<const bf8_t*>(&xlds[(l15 + 16*mt) * XS + k0]);
      bf8_t b0 = *reinterpret_cast<const bf8_t*>(wr0 + k0);
      bf8_t b1 = *reinterpret_cast<const bf8_t*>(wr1 + k0);
      bf8_t b2 = *reinterpret_cast<const bf8_t*>(wr2 + k0);
      bf8_t b3 = *reinterpret_cast<const bf8_t*>(wr3 + k0);
      #pragma unroll
      for (int mt = 0; mt < 4; mt++){
        accA[mt][0] = __builtin_amdgcn_mfma_f32_16x16x32_bf16(a[mt], b0, accA[mt][0], 0, 0, 0);
        accA[mt][1] = __builtin_amdgcn_mfma_f32_16x16x32_bf16(a[mt], b1, accA[mt][1], 0, 0, 0);
        accA[mt][2] = __builtin_amdgcn_mfma_f32_16x16x32_bf16(a[mt], b2, accA[mt][2], 0, 0, 0);
        accA[mt][3] = __builtin_amdgcn_mfma_f32_16x16x32_bf16(a[mt], b3, accA[mt][3], 0, 0, 0);
      }
    }
    // L2-normalize q (scale folded) and k, per row over the head's 32 cols
    float qs = scf[h];
    #pragma unroll
    for (int mt = 0; mt < 4; mt++){
      #pragma unroll
      for (int r = 0; r < 4; r++){
        float q0 = accA[mt][0][r], q1 = accA[mt][1][r];
        float sq = q0*q0 + q1*q1;
        sq += __shfl_xor(sq, 1); sq += __shfl_xor(sq, 2);
        sq += __shfl_xor(sq, 4); sq += __shfl_xor(sq, 8);
        float iv = qs / fmaxf(sqrtf(sq), 1e-12f);
        accA[mt][0][r] = q0 * iv; accA[mt][1][r] = q1 * iv;
        float k0v = accA[mt][2][r], k1v = accA[mt][3][r];
        float sk = k0v*k0v + k1v*k1v;
        sk += __shfl_xor(sk, 1); sk += __shfl_xor(sk, 2);
        sk += __shfl_xor(sk, 4); sk += __shfl_xor(sk, 8);
        float ik = 1.0f / fmaxf(sqrtf(sk), 1e-12f);
        accA[mt][2][r] = k0v * ik; accA[mt][3][r] = k1v * ik;
      }
    }
    // transpose q via per-wave scratch -> A-frags
    #pragma unroll
    for (int mt = 0; mt < 4; mt++)
      #pragma unroll
      for (int dn = 0; dn < 2; dn++)
        #pragma unroll
        for (int r = 0; r < 4; r++)
          wb[(16*mt + 4*l4 + r) * 40 + dn*16 + l15] = f2bf(accA[mt][dn][r]);
    LDSFENCE();
    #pragma unroll
    for (int mt = 0; mt < 4; mt++)
      qa[mt] = *reinterpret_cast<const bf8_t*>(&wb[(l15 + 16*mt) * 40 + l4 * 8]);
    LDSFENCE();
    // transpose k -> B-frags (same layout)
    #pragma unroll
    for (int mt = 0; mt < 4; mt++)
      #pragma unroll
      for (int dn = 0; dn < 2; dn++)
        #pragma unroll
        for (int r = 0; r < 4; r++)
          wb[(16*mt + 4*l4 + r) * 40 + dn*16 + l15] = f2bf(accA[mt][2+dn][r]);
    LDSFENCE();
    #pragma unroll
    for (int nt = 0; nt < 4; nt++)
      kb[nt] = *reinterpret_cast<const bf8_t*>(&wb[(l15 + 16*nt) * 40 + l4 * 8]);
    LDSFENCE();
  }

  // ---- pass B: v for head h ----
  {
    f4_t accV[4][2];
    float bv0 = vbias[32*h + l15], bv1 = vbias[32*h + 16 + l15];
    #pragma unroll
    for (int mt = 0; mt < 4; mt++){
      accV[mt][0] = f4_t{bv0, bv0, bv0, bv0};
      accV[mt][1] = f4_t{bv1, bv1, bv1, bv1};
    }
    const u16* wr0 = wq + (size_t)(512 + 32*h      + l15) * 256;
    const u16* wr1 = wq + (size_t)(512 + 32*h + 16 + l15) * 256;
    #pragma unroll 2
    for (int ks = 0; ks < 8; ks++){
      int k0 = ks * 32 + l4 * 8;
      bf8_t a[4];
      #pragma unroll
      for (int mt = 0; mt < 4; mt++)
        a[mt] = *reinterpret_cast<const bf8_t*>(&xlds[(l15 + 16*mt) * XS + k0]);
      bf8_t b0 = *reinterpret_cast<const bf8_t*>(wr0 + k0);
      bf8_t b1 = *reinterpret_cast<const bf8_t*>(wr1 + k0);
      #pragma unroll
      for (int mt = 0; mt < 4; mt++){
        accV[mt][0] = __builtin_amdgcn_mfma_f32_16x16x32_bf16(a[mt], b0, accV[mt][0], 0, 0, 0);
        accV[mt][1] = __builtin_amdgcn_mfma_f32_16x16x32_bf16(a[mt], b1, accV[mt][1], 0, 0, 0);
      }
    }
    // scatter v transposed ([32 d][64 keys], stride 72) and read PV B-frags
    #pragma unroll
    for (int mt = 0; mt < 4; mt++)
      #pragma unroll
      for (int dn = 0; dn < 2; dn++)
        #pragma unroll
        for (int r = 0; r < 4; r++)
          wb[(dn*16 + l15) * 72 + 16*mt + 4*l4 + r] = f2bf(accV[mt][dn][r]);
    LDSFENCE();
    #pragma unroll
    for (int nt = 0; nt < 2; nt++)
      #pragma unroll
      for (int kh = 0; kh < 2; kh++)
        vv[nt][kh] = *reinterpret_cast<const bf8_t*>(&wb[(l15 + 16*nt) * 72 + kh*32 + l4*8]);
    LDSFENCE();
  }

  // ---- attention for head h (all wave-private) ----
  f4_t accO[4][2];
  {
    f4_t accS[4][4];
    const f4_t* bF = reinterpret_cast<const f4_t*>(biasF) + (size_t)h * 16 * 64;
    #pragma unroll
    for (int mt = 0; mt < 4; mt++)
      #pragma unroll
      for (int nt = 0; nt < 4; nt++)
        accS[mt][nt] = bF[(mt*4 + nt) * 64 + lane];
    #pragma unroll
    for (int mt = 0; mt < 4; mt++)
      #pragma unroll
      for (int nt = 0; nt < 4; nt++)
        accS[mt][nt] = __builtin_amdgcn_mfma_f32_16x16x32_bf16(qa[mt], kb[nt], accS[mt][nt], 0, 0, 0);
    // softmax in log2 domain; fold 1/rowsum into the P scatter
    float invr[4][4];
    #pragma unroll
    for (int mt = 0; mt < 4; mt++){
      #pragma unroll
      for (int r = 0; r < 4; r++){
        float mx = fmaxf(fmaxf(accS[mt][0][r], accS[mt][1][r]),
                         fmaxf(accS[mt][2][r], accS[mt][3][r]));
        mx = fmaxf(mx, __shfl_xor(mx, 1)); mx = fmaxf(mx, __shfl_xor(mx, 2));
        mx = fmaxf(mx, __shfl_xor(mx, 4)); mx = fmaxf(mx, __shfl_xor(mx, 8));
        float s = 0.f;
        #pragma unroll
        for (int nt = 0; nt < 4; nt++){
          float p = exp2f(accS[mt][nt][r] - mx);
          accS[mt][nt][r] = p; s += p;
        }
        s += __shfl_xor(s, 1); s += __shfl_xor(s, 2);
        s += __shfl_xor(s, 4); s += __shfl_xor(s, 8);
        invr[mt][r] = 1.0f / s;
      }
    }
    #pragma unroll
    for (int mt = 0; mt < 4; mt++){ accO[mt][0] = f4_t{0,0,0,0}; accO[mt][1] = f4_t{0,0,0,0}; }
    #pragma unroll
    for (int kh = 0; kh < 2; kh++){
      #pragma unroll
      for (int mt = 0; mt < 4; mt++)
        #pragma unroll
        for (int dn = 0; dn < 2; dn++)
          #pragma unroll
          for (int r = 0; r < 4; r++)
            wb[(16*mt + 4*l4 + r) * 40 + dn*16 + l15] = f2bf(accS[mt][2*kh+dn][r] * invr[mt][r]);
      LDSFENCE();
      bf8_t pa[4];
      #pragma unroll
      for (int mt = 0; mt < 4; mt++)
        pa[mt] = *reinterpret_cast<const bf8_t*>(&wb[(l15 + 16*mt) * 40 + l4 * 8]);
      LDSFENCE();
      #pragma unroll
      for (int mt = 0; mt < 4; mt++)
        #pragma unroll
        for (int nt = 0; nt < 2; nt++)
          accO[mt][nt] = __builtin_amdgcn_mfma_f32_16x16x32_bf16(pa[mt], vv[nt][kh], accO[mt][nt], 0, 0, 0);
    }
  }
  __syncthreads();                                  // all waves done reading x from xlds

  // ---- O (bf16) -> xlds (aliases dead x tile) ----
  #pragma unroll
  for (int mt = 0; mt < 4; mt++)
    #pragma unroll
    for (int dn = 0; dn < 2; dn++)
      #pragma unroll
      for (int r = 0; r < 4; r++)
        xlds[(16*mt + 4*l4 + r) * XS + 32*h + dn*16 + l15] = f2bf(accO[mt][dn][r]);
  __syncthreads();

  // ---- output projection (wave w owns cols [32w, 32w+32)) ----
  {
    f4_t accP[4][2];
    float pb0 = projb[32*w + l15], pb1 = projb[32*w + 16 + l15];
    #pragma unroll
    for (int mt = 0; mt < 4; mt++){
      accP[mt][0] = f4_t{pb0, pb0, pb0, pb0};
      accP[mt][1] = f4_t{pb1, pb1, pb1, pb1};
    }
    const u16* wr0 = wp + (size_t)(32*w      + l15) * 256;
    const u16* wr1 = wp + (size_t)(32*w + 16 + l15) * 256;
    #pragma unroll 2
    for (int ks = 0; ks < 8; ks++){
      int k0 = ks * 32 + l4 * 8;
      bf8_t a[4];
      #pragma unroll
      for (int mt = 0; mt < 4; mt++)
        a[mt] = *reinterpret_cast<const bf8_t*>(&xlds[(l15 + 16*mt) * XS + k0]);
      bf8_t b0 = *reinterpret_cast<const bf8_t*>(wr0 + k0);
      bf8_t b1 = *reinterpret_cast<const bf8_t*>(wr1 + k0);
      #pragma unroll
      for (int mt = 0; mt < 4; mt++){
        accP[mt][0] = __builtin_amdgcn_mfma_f32_16x16x32_bf16(a[mt], b0, accP[mt][0], 0, 0, 0);
        accP[mt][1] = __builtin_amdgcn_mfma_f32_16x16x32_bf16(a[mt], b1, accP[mt][1], 0, 0, 0);
      }
    }
    float* og = out + (size_t)b * 16384;
    #pragma unroll
    for (int mt = 0; mt < 4; mt++)
      #pragma unroll
      for (int nt = 0; nt < 2; nt++)
        #pragma unroll
        for (int r = 0; r < 4; r++)
          og[(16*mt + 4*l4 + r) * 256 + 32*w + nt*16 + l15] = accP[mt][nt][r];
  }
}

// ---------------- launch ----------------
extern "C" void kernel_launch(void* const* d_in, const int* in_sizes, int n_in,
                              void* d_out, int out_size, void* d_ws, size_t ws_size,
                              hipStream_t stream){
  const float* x     = (const float*)d_in[0];
  const float* qkvw  = (const float*)d_in[1];
  const float* qb    = (const float*)d_in[2];
  const float* vb    = (const float*)d_in[3];
  const float* scale = (const float*)d_in[4];
  const float* w1    = (const float*)d_in[5];
  const float* b1    = (const float*)d_in[6];
  const float* w2    = (const float*)d_in[7];
  const float* pw    = (const float*)d_in[8];
  const float* pb    = (const float*)d_in[9];
  const float* tab   = (const float*)d_in[10];
  const int*   idx   = (const int*)d_in[11];
  float* out = (float*)d_out;

  char* ws = (char*)d_ws;
  u16*   wqb  = (u16*)ws;                    // 393216 B : qkv_w bf16
  u16*   wpb  = (u16*)(ws + 393216);         // 131072 B : proj_w bf16
  float* bias = (float*)(ws + 524288);       // 131072 B : CPB bias in C-frag order
  float* tbl  = (float*)(ws + 655360);       //   7200 B : cpb MLP out [225][8]
  float* scfp = (float*)(ws + 662560);       //     32 B : folded per-head scale

  hipLaunchKernelGGL(wconv_kernel,    dim3(256), dim3(256), 0, stream, qkvw, pw, wqb, wpb);
  hipLaunchKernelGGL(cpbmlp_kernel,   dim3(8),   dim3(256), 0, stream, tab, w1, b1, w2, tbl);
  hipLaunchKernelGGL(cpbgather_kernel,dim3(128), dim3(256), 0, stream, tbl, idx, scale, bias, scfp);
  hipLaunchKernelGGL(winattn_kernel,  dim3(2048), dim3(512), 0, stream,
                     x, wqb, wpb, qb, vb, bias, scfp, pb, out);
}

// Round 4
// 191.110 us; speedup vs baseline: 1.7108x; 1.2048x over previous
//
#include <hip/hip_runtime.h>
#include <stdint.h>

typedef unsigned short u16;
typedef unsigned int u32;
typedef short bf8_t __attribute__((ext_vector_type(8)));   // 8 bf16 = 4 VGPR
typedef float f4_t  __attribute__((ext_vector_type(4)));
typedef float f16_t __attribute__((ext_vector_type(16)));  // 32x32 MFMA C/D

#define LOG2E 1.44269504088896340736f

// packed f32x2 -> bf16x2 (RNE), single instruction
static __device__ __forceinline__ u32 pkbf(float lo, float hi){
  u32 r; asm("v_cvt_pk_bf16_f32 %0, %1, %2" : "=v"(r) : "v"(lo), "v"(hi)); return r;
}

// Convert one 32x32 C'-tile (lane = n-col l31, regs = m per C-layout
// m=(r&3)+8*(r>>2)+4*l5) into two A/B frags with frag-k = m:
// f0 covers m=0..15, f1 covers m=16..31. Output frag lane l, u32[i] holds
// m = 8*l5 + 2i, 2i+1 (f0) / 16 + that (f1). Own half provides pk pairs;
// the other 8 m's live at lane^32 -> one shfl_xor(32) per pair-slot.
static __device__ __forceinline__ void cvt_tile(const f16_t c, bool hi5, bf8_t& f0, bf8_t& f1){
  u32 p0 = pkbf(c[0], c[1]),  p1 = pkbf(c[2], c[3]);
  u32 p2 = pkbf(c[4], c[5]),  p3 = pkbf(c[6], c[7]);
  u32 p4 = pkbf(c[8], c[9]),  p5 = pkbf(c[10], c[11]);
  u32 p6 = pkbf(c[12], c[13]), p7 = pkbf(c[14], c[15]);
  u32 t0 = hi5 ? p0 : p2,  t1 = hi5 ? p1 : p3;
  u32 t2 = hi5 ? p4 : p6,  t3 = hi5 ? p5 : p7;
  u32 s0 = (u32)__shfl_xor((int)t0, 32);
  u32 s1 = (u32)__shfl_xor((int)t1, 32);
  u32 s2 = (u32)__shfl_xor((int)t2, 32);
  u32 s3 = (u32)__shfl_xor((int)t3, 32);
  union { u32 u[4]; bf8_t b; } x0, x1;
  x0.u[0] = hi5 ? s0 : p0;  x0.u[1] = hi5 ? s1 : p1;
  x0.u[2] = hi5 ? p2 : s0;  x0.u[3] = hi5 ? p3 : s1;
  x1.u[0] = hi5 ? s2 : p4;  x1.u[1] = hi5 ? s3 : p5;
  x1.u[2] = hi5 ? p6 : s2;  x1.u[3] = hi5 ? p7 : s3;
  f0 = x0.b; f1 = x1.b;
}

#define MFMA32(a, b, c) __builtin_amdgcn_mfma_f32_32x32x16_bf16(a, b, c, 0, 0, 0)

// ---------------- pre-kernels ----------------

__global__ void wconv_kernel(const float* __restrict__ qkvw, const float* __restrict__ projw,
                             u16* __restrict__ wq, u16* __restrict__ wp){
  int i4 = blockIdx.x * blockDim.x + threadIdx.x;
  const float* src; u16* dst; int off;
  if (i4 < 49152){ src = qkvw; dst = wq; off = i4 * 4; }
  else           { src = projw; dst = wp; off = (i4 - 49152) * 4; }
  float4 v = *reinterpret_cast<const float4*>(src + off);
  uint2 p; p.x = pkbf(v.x, v.y); p.y = pkbf(v.z, v.w);
  *reinterpret_cast<uint2*>(dst + off) = p;
}

__global__ void cpbmlp_kernel(const float* __restrict__ tab, const float* __restrict__ w1,
                              const float* __restrict__ b1, const float* __restrict__ w2,
                              float* __restrict__ tbl){
  int u = blockIdx.x * blockDim.x + threadIdx.x;
  if (u >= 225 * 8) return;
  int i = u >> 3, h = u & 7;
  float c0 = tab[2*i], c1 = tab[2*i+1];
  const float* w2h = w2 + h * 512;
  float acc = 0.f;
  for (int j = 0; j < 512; j++){
    float hv = fmaf(c1, w1[2*j+1], fmaf(c0, w1[2*j], b1[j]));
    hv = fmaxf(hv, 0.f);
    acc = fmaf(hv, w2h[j], acc);
  }
  tbl[i*8 + h] = acc;
}

// bias for S^T = K.Q^T C-layout: biasF[(((h*4 + kt*2 + qt)*4 + r4)*64 + lane)*4 + rl]
//   = 16*sigmoid(cpb[h, query, key]) * log2e
// query = 32*qt + (lane&31); key = 32*kt + rl + 8*r4 + 4*(lane>>5)
__global__ void cpbgather_kernel(const float* __restrict__ tbl, const int* __restrict__ idx,
                                 const float* __restrict__ scale, float* __restrict__ biasF,
                                 float* __restrict__ scf){
  int u = blockIdx.x * blockDim.x + threadIdx.x;   // 0..32767
  int rl   = u & 3;
  int lane = (u >> 2) & 63;
  int r4   = (u >> 8) & 3;
  int tile = (u >> 10) & 3;       // kt*2 + qt
  int hh   = (u >> 12) & 7;
  int qt = tile & 1, kt = tile >> 1;
  int query = 32*qt + (lane & 31);
  int key   = 32*kt + rl + 8*r4 + 4*(lane >> 5);
  int id = idx[query*64 + key];
  float xv = tbl[id*8 + hh];
  float s = 1.f / (1.f + expf(-xv));
  biasF[u] = 16.f * s * LOG2E;
  if (u < 8){
    float sc = fminf(scale[u], 4.6051701859880913680f);  // log(100)
    scf[u] = expf(sc) * LOG2E;
  }
}

// ---------------- main fused kernel ----------------
// 1 block/window, 8 waves, wave w = head w end-to-end, 32x32x16 MFMAs.
// All layout changes done in-register (cvt_tile); zero LDS transposes.
#define XS 264    // x / O tile stride in u16 (256+8); 528 B

__global__ __launch_bounds__(512, 4)
void winattn_kernel(const float* __restrict__ x, const u16* __restrict__ wq,
                    const u16* __restrict__ wp, const float* __restrict__ qb,
                    const float* __restrict__ vbias, const float* __restrict__ biasF,
                    const float* __restrict__ scf, const float* __restrict__ projb,
                    float* __restrict__ out){
  __shared__ u16 xlds[64 * XS];   // x bf16
  __shared__ u16 olds[64 * XS];   // attention output bf16

  const int b = blockIdx.x;
  const int t = threadIdx.x;
  const int w = t >> 6, lane = t & 63;
  const int l31 = lane & 31, l5 = lane >> 5;
  const bool hi5 = (l5 != 0);
  const int h = w;

  // ---- phase 0: stage x[b] -> LDS bf16 ----
  {
    const float* xg = x + (size_t)b * 16384;
    #pragma unroll
    for (int i = 0; i < 8; i++){
      int fi = t + 512 * i;
      float4 v = *reinterpret_cast<const float4*>(xg + fi * 4);
      uint2 p; p.x = pkbf(v.x, v.y); p.y = pkbf(v.z, v.w);
      int row = fi >> 6, c = (fi & 63) * 4;
      *reinterpret_cast<uint2*>(&xlds[row * XS + c]) = p;
    }
  }
  __syncthreads();

  bf8_t qf00, qf01, qf10, qf11;   // q B-frags [token-tile][k-block over d]
  bf8_t kf00, kf01, kf10, kf11;   // k A-frags
  bf8_t vf0, vf1, vf2, vf3;       // v A-frags [key-block]

  // ---- phase A: q,k transposed GEMM (A = W rows, B = x tokens) ----
  {
    f16_t cq0, cq1, ck0, ck1;     // C'[d][token], token tiles 0/1
    #pragma unroll
    for (int r = 0; r < 16; r++){
      float bqr = qb[32*h + (r & 3) + 8*(r >> 2) + 4*l5];
      cq0[r] = bqr; cq1[r] = bqr; ck0[r] = 0.f; ck1[r] = 0.f;
    }
    const u16* wqr = wq + (size_t)(32*h + l31) * 256;
    const u16* wkr = wqr + 256 * 256;
    #pragma unroll 4
    for (int ks = 0; ks < 16; ks++){
      const int ko = ks * 16 + 8 * l5;
      bf8_t aq  = *reinterpret_cast<const bf8_t*>(wqr + ko);
      bf8_t ak  = *reinterpret_cast<const bf8_t*>(wkr + ko);
      bf8_t bx0 = *reinterpret_cast<const bf8_t*>(&xlds[l31 * XS + ko]);
      bf8_t bx1 = *reinterpret_cast<const bf8_t*>(&xlds[(32 + l31) * XS + ko]);
      cq0 = MFMA32(aq, bx0, cq0);
      cq1 = MFMA32(aq, bx1, cq1);
      ck0 = MFMA32(ak, bx0, ck0);
      ck1 = MFMA32(ak, bx1, ck1);
    }
    // per-token L2 norm over d (in-register + one lane^32 exchange)
    float qs = scf[h];
    {
      float sq = 0.f, sk = 0.f;
      #pragma unroll
      for (int r = 0; r < 16; r++){ sq = fmaf(cq0[r], cq0[r], sq); sk = fmaf(ck0[r], ck0[r], sk); }
      sq += __shfl_xor(sq, 32); sk += __shfl_xor(sk, 32);
      float iq = qs * __builtin_amdgcn_rsqf(fmaxf(sq, 1e-24f));
      float ik = __builtin_amdgcn_rsqf(fmaxf(sk, 1e-24f));
      #pragma unroll
      for (int r = 0; r < 16; r++){ cq0[r] *= iq; ck0[r] *= ik; }
      cvt_tile(cq0, hi5, qf00, qf01);
      cvt_tile(ck0, hi5, kf00, kf01);
    }
    {
      float sq = 0.f, sk = 0.f;
      #pragma unroll
      for (int r = 0; r < 16; r++){ sq = fmaf(cq1[r], cq1[r], sq); sk = fmaf(ck1[r], ck1[r], sk); }
      sq += __shfl_xor(sq, 32); sk += __shfl_xor(sk, 32);
      float iq = qs * __builtin_amdgcn_rsqf(fmaxf(sq, 1e-24f));
      float ik = __builtin_amdgcn_rsqf(fmaxf(sk, 1e-24f));
      #pragma unroll
      for (int r = 0; r < 16; r++){ cq1[r] *= iq; ck1[r] *= ik; }
      cvt_tile(cq1, hi5, qf10, qf11);
      cvt_tile(ck1, hi5, kf10, kf11);
    }
  }

  // ---- phase B: v normal GEMM (A = x tokens, B = Wv rows) -> C[token][d] ----
  {
    f16_t cv0, cv1;
    float bv = vbias[32*h + l31];
    #pragma unroll
    for (int r = 0; r < 16; r++){ cv0[r] = bv; cv1[r] = bv; }
    const u16* wvr = wq + (size_t)(512 + 32*h + l31) * 256;
    #pragma unroll 4
    for (int ks = 0; ks < 16; ks++){
      const int ko = ks * 16 + 8 * l5;
      bf8_t bw  = *reinterpret_cast<const bf8_t*>(wvr + ko);
      bf8_t ax0 = *reinterpret_cast<const bf8_t*>(&xlds[l31 * XS + ko]);
      bf8_t ax1 = *reinterpret_cast<const bf8_t*>(&xlds[(32 + l31) * XS + ko]);
      cv0 = MFMA32(ax0, bw, cv0);
      cv1 = MFMA32(ax1, bw, cv1);
    }
    cvt_tile(cv0, hi5, vf0, vf1);   // keys  0..31 -> k-blocks 0,1
    cvt_tile(cv1, hi5, vf2, vf3);   // keys 32..63 -> k-blocks 2,3
  }

  // ---- phase S: S^T = K.Q^T (+bias C-init), softmax, O^T = V.P ----
  #pragma unroll
  for (int nt = 0; nt < 2; nt++){                 // query tile
    f16_t s0, s1;                                 // key tiles 0,1
    {
      const f4_t* b0 = reinterpret_cast<const f4_t*>(biasF) + (h*4 + nt    ) * 256 + lane;
      const f4_t* b1 = reinterpret_cast<const f4_t*>(biasF) + (h*4 + 2 + nt) * 256 + lane;
      #pragma unroll
      for (int r4 = 0; r4 < 4; r4++){
        f4_t q0 = b0[r4 * 64], q1 = b1[r4 * 64];
        #pragma unroll
        for (int i = 0; i < 4; i++){ s0[4*r4 + i] = q0[i]; s1[4*r4 + i] = q1[i]; }
      }
    }
    bf8_t qfa = nt ? qf10 : qf00, qfb = nt ? qf11 : qf01;
    s0 = MFMA32(kf00, qfa, s0); s0 = MFMA32(kf01, qfb, s0);
    s1 = MFMA32(kf10, qfa, s1); s1 = MFMA32(kf11, qfb, s1);
    // softmax over keys: lane pair (l, l^32) splits the keys of query l31 —
    // reduce in-register, then ONE lane^32 exchange for max and for sum.
    f16_t tm;
    #pragma unroll
    for (int r = 0; r < 16; r++) tm[r] = fmaxf(s0[r], s1[r]);
    #pragma unroll
    for (int r = 0; r < 8; r++) tm[r] = fmaxf(tm[r], tm[r+8]);
    #pragma unroll
    for (int r = 0; r < 4; r++) tm[r] = fmaxf(tm[r], tm[r+4]);
    float mx = fmaxf(fmaxf(tm[0], tm[1]), fmaxf(tm[2], tm[3]));
    mx = fmaxf(mx, __shfl_xor(mx, 32));           // other key-half, same query
    #pragma unroll
    for (int r = 0; r < 16; r++){ s0[r] = exp2f(s0[r] - mx); s1[r] = exp2f(s1[r] - mx); }
    float a0 = 0.f, a1 = 0.f, a2 = 0.f, a3 = 0.f;
    #pragma unroll
    for (int r4 = 0; r4 < 4; r4++){
      a0 += s0[4*r4 + 0] + s1[4*r4 + 0];
      a1 += s0[4*r4 + 1] + s1[4*r4 + 1];
      a2 += s0[4*r4 + 2] + s1[4*r4 + 2];
      a3 += s0[4*r4 + 3] + s1[4*r4 + 3];
    }
    float ssum = (a0 + a1) + (a2 + a3);
    ssum += __shfl_xor(ssum, 32);                 // other key-half, same query
    float invr = __builtin_amdgcn_rcpf(ssum);     // per-query (pair-consistent)
    bf8_t pf0, pf1, pf2, pf3;
    cvt_tile(s0, hi5, pf0, pf1);
    cvt_tile(s1, hi5, pf2, pf3);
    f16_t co;
    #pragma unroll
    for (int r = 0; r < 16; r++) co[r] = 0.f;
    co = MFMA32(vf0, pf0, co); co = MFMA32(vf1, pf1, co);
    co = MFMA32(vf2, pf2, co); co = MFMA32(vf3, pf3, co);
    // O^T[d][query]: lane = query; fold 1/rowsum; contiguous b64 stores
    #pragma unroll
    for (int r4 = 0; r4 < 4; r4++){
      uint2 p;
      p.x = pkbf(co[4*r4 + 0] * invr, co[4*r4 + 1] * invr);
      p.y = pkbf(co[4*r4 + 2] * invr, co[4*r4 + 3] * invr);
      *reinterpret_cast<uint2*>(&olds[(32*nt + l31) * XS + 32*h + 8*r4 + 4*l5]) = p;
    }
  }
  __syncthreads();

  // ---- proj: out cols [32w,32w+32), A = O tokens (LDS), B = Wp rows ----
  {
    f16_t cp0, cp1;
    float pbv = projb[32*w + l31];
    #pragma unroll
    for (int r = 0; r < 16; r++){ cp0[r] = pbv; cp1[r] = pbv; }
    const u16* wpr = wp + (size_t)(32*w + l31) * 256;
    #pragma unroll 4
    for (int ks = 0; ks < 16; ks++){
      const int ko = ks * 16 + 8 * l5;
      bf8_t bw = *reinterpret_cast<const bf8_t*>(wpr + ko);
      bf8_t a0 = *reinterpret_cast<const bf8_t*>(&olds[l31 * XS + ko]);
      bf8_t a1 = *reinterpret_cast<const bf8_t*>(&olds[(32 + l31) * XS + ko]);
      cp0 = MFMA32(a0, bw, cp0);
      cp1 = MFMA32(a1, bw, cp1);
    }
    float* og = out + (size_t)b * 16384;
    #pragma unroll
    for (int r = 0; r < 16; r++){
      int m = (r & 3) + 8*(r >> 2) + 4*l5;
      og[m * 256 + 32*w + l31] = cp0[r];
      og[(32 + m) * 256 + 32*w + l31] = cp1[r];
    }
  }
}

// ---------------- launch ----------------
extern "C" void kernel_launch(void* const* d_in, const int* in_sizes, int n_in,
                              void* d_out, int out_size, void* d_ws, size_t ws_size,
                              hipStream_t stream){
  const float* x     = (const float*)d_in[0];
  const float* qkvw  = (const float*)d_in[1];
  const float* qb    = (const float*)d_in[2];
  const float* vb    = (const float*)d_in[3];
  const float* scale = (const float*)d_in[4];
  const float* w1    = (const float*)d_in[5];
  const float* b1    = (const float*)d_in[6];
  const float* w2    = (const float*)d_in[7];
  const float* pw    = (const float*)d_in[8];
  const float* pb    = (const float*)d_in[9];
  const float* tab   = (const float*)d_in[10];
  const int*   idx   = (const int*)d_in[11];
  float* out = (float*)d_out;

  char* ws = (char*)d_ws;
  u16*   wqb  = (u16*)ws;                    // 393216 B : qkv_w bf16
  u16*   wpb  = (u16*)(ws + 393216);         // 131072 B : proj_w bf16
  float* bias = (float*)(ws + 524288);       // 131072 B : CPB bias in S^T C-frag order
  float* tbl  = (float*)(ws + 655360);       //   7200 B : cpb MLP out [225][8]
  float* scfp = (float*)(ws + 662560);       //     32 B : folded per-head scale

  hipLaunchKernelGGL(wconv_kernel,    dim3(256), dim3(256), 0, stream, qkvw, pw, wqb, wpb);
  hipLaunchKernelGGL(cpbmlp_kernel,   dim3(8),   dim3(256), 0, stream, tab, w1, b1, w2, tbl);
  hipLaunchKernelGGL(cpbgather_kernel,dim3(128), dim3(256), 0, stream, tbl, idx, scale, bias, scfp);
  hipLaunchKernelGGL(winattn_kernel,  dim3(2048), dim3(512), 0, stream,
                     x, wqb, wpb, qb, vb, bias, scfp, pb, out);
}